// Round 1
// baseline (838.303 us; speedup 1.0000x reference)
//
#include <hip/hip_runtime.h>
#include <cmath>
#include <cstdint>
#include <cstddef>

#define NB 8
#define NPTS 1024
#define BN (NB*NPTS)
#define KNN 20
#define XC_C 512
#define BN_SC 0.99999500003749973f  // 1/sqrt(1+1e-5)

static __device__ __forceinline__ float lrelu(float z) { return z >= 0.f ? z : 0.01f * z; }

// ---- prep: x (B,N,3) -> ft (B,3,N) + norms ----
__global__ void prep_k(const float* __restrict__ x, float* __restrict__ ft, float* __restrict__ nrm) {
    int i = blockIdx.x * 256 + threadIdx.x;   // b*N+n
    if (i >= BN) return;
    int b = i >> 10, n = i & 1023;
    float a = x[3*i], c = x[3*i+1], d = x[3*i+2];
    float* fb = ft + (size_t)b * 3 * NPTS;
    fb[n] = a; fb[NPTS + n] = c; fb[2*NPTS + n] = d;
    nrm[i] = a*a + c*c + d*d;
}

// ---- fused knn: dist (2*inner - xx[m], constant-shift preserves jax ordering+ties) + top-20 ----
// grid BN/4 blocks x 256 threads; one wave per row n.
template<int C>
__global__ __launch_bounds__(256) void knn_k(const float* __restrict__ ft, const float* __restrict__ nrm,
                                             int* __restrict__ idx) {
    int r = blockIdx.x * 4 + (threadIdx.x >> 6);
    int lane = threadIdx.x & 63;
    int b = r >> 10, n = r & 1023;
    const float* ftb = ft + (size_t)b * C * NPTS;
    float4 acc[4];
#pragma unroll
    for (int j = 0; j < 4; j++) acc[j] = make_float4(0.f, 0.f, 0.f, 0.f);
    for (int c = 0; c < C; c++) {
        float ctr = ftb[(size_t)c * NPTS + n];                      // broadcast within wave
        const float4* rm = (const float4*)(ftb + (size_t)c * NPTS); // coalesced m-stream
#pragma unroll
        for (int j = 0; j < 4; j++) {
            float4 v = rm[lane + 64*j];
            acc[j].x = fmaf(ctr, v.x, acc[j].x);
            acc[j].y = fmaf(ctr, v.y, acc[j].y);
            acc[j].z = fmaf(ctr, v.z, acc[j].z);
            acc[j].w = fmaf(ctr, v.w, acc[j].w);
        }
    }
    float key[16];
    const float4* nm4 = (const float4*)(nrm + b * NPTS);
#pragma unroll
    for (int j = 0; j < 4; j++) {
        float4 nm = nm4[lane + 64*j];
        key[4*j+0] = 2.f*acc[j].x - nm.x;
        key[4*j+1] = 2.f*acc[j].y - nm.y;
        key[4*j+2] = 2.f*acc[j].z - nm.z;
        key[4*j+3] = 2.f*acc[j].w - nm.w;
    }
    int* out = idx + r * KNN;
    for (int kk = 0; kk < KNN; kk++) {
        float bv = -INFINITY; int bm = 0x7fffffff;
#pragma unroll
        for (int j = 0; j < 4; j++)
#pragma unroll
            for (int q = 0; q < 4; q++) {
                float v = key[4*j+q];
                int m = 4*(lane + 64*j) + q;   // ascending within lane -> strict > keeps lowest m
                if (v > bv) { bv = v; bm = m; }
            }
#pragma unroll
        for (int off = 32; off > 0; off >>= 1) {  // butterfly argmax, lowest-index tiebreak
            float ov = __shfl_xor(bv, off);
            int   om = __shfl_xor(bm, off);
            if (ov > bv || (ov == bv && om < bm)) { bv = ov; bm = om; }
        }
        if (lane == 0) out[kk] = bm;
        if (((bm >> 2) & 63) == lane) {
            int slot = ((bm >> 8) << 2) | (bm & 3);
#pragma unroll
            for (int t = 0; t < 16; t++) if (t == slot) key[t] = -INFINITY;
        }
    }
}

// ---- H/Ct GEMM: Ht[n,o]=F.w1; Ct[n,o]=F.w2 - Ht + bias ----
// grid BN/4, block O; 4 rows per block for w-reuse.
template<int C, int O, bool HASB>
__global__ void hc_k(const float* __restrict__ F, int FS,
                     const float* __restrict__ w, const float* __restrict__ bias,
                     float* __restrict__ Ht, float* __restrict__ Ct) {
    int r0 = blockIdx.x * 4;
    int o = threadIdx.x;
    const float* wr = w + (size_t)o * (2*C);
    float h[4] = {0,0,0,0}, a2[4] = {0,0,0,0};
    if constexpr ((C & 3) == 0) {
        const float4* w1 = (const float4*)wr;
        const float4* w2 = (const float4*)(wr + C);
#pragma unroll 4
        for (int c4 = 0; c4 < C/4; c4++) {
            float4 wa = w1[c4], wb = w2[c4];
#pragma unroll
            for (int nn = 0; nn < 4; nn++) {
                float4 f = *(const float4*)(F + (size_t)(r0+nn)*FS + 4*c4);  // broadcast
                h[nn]  = fmaf(wa.x,f.x, fmaf(wa.y,f.y, fmaf(wa.z,f.z, fmaf(wa.w,f.w, h[nn]))));
                a2[nn] = fmaf(wb.x,f.x, fmaf(wb.y,f.y, fmaf(wb.z,f.z, fmaf(wb.w,f.w, a2[nn]))));
            }
        }
    } else {
        for (int c = 0; c < C; c++) {
            float wa = wr[c], wb = wr[C+c];
#pragma unroll
            for (int nn = 0; nn < 4; nn++) {
                float f = F[(size_t)(r0+nn)*FS + c];
                h[nn]  = fmaf(wa, f, h[nn]);
                a2[nn] = fmaf(wb, f, a2[nn]);
            }
        }
    }
    float bs = 0.f;
    if constexpr (HASB) bs = bias[o];
#pragma unroll
    for (int nn = 0; nn < 4; nn++) {
        size_t ro = (size_t)(r0+nn)*O + o;
        Ht[ro] = h[nn];
        Ct[ro] = a2[nn] - h[nn] + bs;
    }
}

// ---- gather + max_k + bn + lrelu; optional transposed-feature + norms for next knn ----
template<int O, bool WFT>
__global__ void gmax_k(const float* __restrict__ Ht, const float* __restrict__ Ct,
                       const int* __restrict__ idx,
                       const float* __restrict__ g, const float* __restrict__ bb,
                       float* __restrict__ xcs, float* __restrict__ ft, float* __restrict__ nrm) {
    int r = blockIdx.x;
    int b = r >> 10, n = r & 1023;
    int o = threadIdx.x;
    const int* id = idx + r * KNN;
    float vmax = -INFINITY, vmin = INFINITY;
    const float* hb = Ht + (size_t)b * NPTS * O + o;
#pragma unroll 4
    for (int k = 0; k < KNN; k++) {
        int m = id[k];                 // broadcast
        float v = hb[(size_t)m * O];   // coalesced across o
        vmax = fmaxf(vmax, v); vmin = fminf(vmin, v);
    }
    float ct = Ct[(size_t)r * O + o];
    float s = g[o] * BN_SC;
    float pre = (s >= 0.f ? vmax : vmin) + ct;
    float out = lrelu(fmaf(s, pre, bb[o]));
    xcs[(size_t)r * XC_C + o] = out;
    if constexpr (WFT) {
        ft[((size_t)b * O + o) * NPTS + n] = out;
        float sq = out * out;
#pragma unroll
        for (int off = 32; off > 0; off >>= 1) sq += __shfl_xor(sq, off);
        __shared__ float red[O/64 > 0 ? O/64 : 1];
        if ((o & 63) == 0) red[o >> 6] = sq;
        __syncthreads();
        if (o == 0) {
            float t = 0.f;
#pragma unroll
            for (int i = 0; i < O/64; i++) t += red[i];
            nrm[r] = t;
        }
    }
}

// ---- w5 transpose (1024,512) -> (512,1024) for coalesced o-loads ----
__global__ void w5t_k(const float* __restrict__ w5, float* __restrict__ w5t) {
    int i = blockIdx.x * 256 + threadIdx.x;   // c*1024+o
    int c = i >> 10, o = i & 1023;
    w5t[i] = w5[(size_t)o * 512 + c];
}

// ---- conv5 + partial max over n: grid (64 ntiles, B), block 256; thread = 4 o, 16 n ----
__global__ __launch_bounds__(256) void conv5max_k(const float* __restrict__ xc,
                                                  const float* __restrict__ w5t,
                                                  float* __restrict__ part) {
    int b = blockIdx.y, nt = blockIdx.x;
    int o4 = threadIdx.x;
    const float* xb = xc + ((size_t)b * NPTS + nt * 16) * XC_C;
    float4 acc[16];
#pragma unroll
    for (int i = 0; i < 16; i++) acc[i] = make_float4(0.f,0.f,0.f,0.f);
    for (int c = 0; c < 512; c++) {
        float4 w4 = ((const float4*)(w5t + (size_t)c * 1024))[o4];  // coalesced
#pragma unroll
        for (int nn = 0; nn < 16; nn++) {
            float xv = xb[(size_t)nn * XC_C + c];                   // uniform -> scalar path
            acc[nn].x = fmaf(w4.x, xv, acc[nn].x);
            acc[nn].y = fmaf(w4.y, xv, acc[nn].y);
            acc[nn].z = fmaf(w4.z, xv, acc[nn].z);
            acc[nn].w = fmaf(w4.w, xv, acc[nn].w);
        }
    }
    float4 m = acc[0];
#pragma unroll
    for (int nn = 1; nn < 16; nn++) {
        m.x = fmaxf(m.x, acc[nn].x); m.y = fmaxf(m.y, acc[nn].y);
        m.z = fmaxf(m.z, acc[nn].z); m.w = fmaxf(m.w, acc[nn].w);
    }
    ((float4*)(part + ((size_t)b * 64 + nt) * 1024))[o4] = m;
}

// ---- head: reduce partials -> gpool -> lin1/bn6/lrelu -> lin2/bn7/lrelu -> lin3 ----
__global__ __launch_bounds__(256) void head_k(const float* __restrict__ part,
        const float* __restrict__ l1w, const float* __restrict__ g6, const float* __restrict__ b6,
        const float* __restrict__ l2w, const float* __restrict__ l2b,
        const float* __restrict__ g7, const float* __restrict__ b7,
        const float* __restrict__ l3w, const float* __restrict__ l3b,
        float* __restrict__ out) {
    int b = blockIdx.x, t = threadIdx.x;
    __shared__ float gp[1024];
    __shared__ float y1[512];
    __shared__ float y2[256];
    const float* pb = part + (size_t)b * 64 * 1024;
    for (int o = t; o < 1024; o += 256) {
        float m = pb[o];
        for (int j = 1; j < 64; j++) m = fmaxf(m, pb[(size_t)j * 1024 + o]);
        gp[o] = m;
    }
    __syncthreads();
    for (int j = t; j < 512; j += 256) {
        const float4* wr = (const float4*)(l1w + (size_t)j * 1024);
        const float4* g4 = (const float4*)gp;
        float acc = 0.f;
        for (int c = 0; c < 256; c++) {
            float4 w = wr[c], x = g4[c];
            acc = fmaf(w.x,x.x, fmaf(w.y,x.y, fmaf(w.z,x.z, fmaf(w.w,x.w, acc))));
        }
        y1[j] = lrelu(fmaf(acc, g6[j] * BN_SC, b6[j]));
    }
    __syncthreads();
    {
        const float4* wr = (const float4*)(l2w + (size_t)t * 512);
        const float4* y4 = (const float4*)y1;
        float acc = l2b[t];
        for (int c = 0; c < 128; c++) {
            float4 w = wr[c], x = y4[c];
            acc = fmaf(w.x,x.x, fmaf(w.y,x.y, fmaf(w.z,x.z, fmaf(w.w,x.w, acc))));
        }
        y2[t] = lrelu(fmaf(acc, g7[t] * BN_SC, b7[t]));
    }
    __syncthreads();
    if (t < 40) {
        const float4* wr = (const float4*)(l3w + (size_t)t * 256);
        const float4* y4 = (const float4*)y2;
        float acc = l3b[t];
        for (int c = 0; c < 64; c++) {
            float4 w = wr[c], x = y4[c];
            acc = fmaf(w.x,x.x, fmaf(w.y,x.y, fmaf(w.z,x.z, fmaf(w.w,x.w, acc))));
        }
        out[b * 40 + t] = acc;
    }
}

extern "C" void kernel_launch(void* const* d_in, const int* in_sizes, int n_in,
                              void* d_out, int out_size, void* d_ws, size_t ws_size,
                              hipStream_t stream) {
    const float* x       = (const float*)d_in[0];
    const float* conv1_w = (const float*)d_in[1];
    const float* conv1_b = (const float*)d_in[2];
    const float* bn1_g   = (const float*)d_in[3];
    const float* bn1_b   = (const float*)d_in[4];
    const float* conv2_w = (const float*)d_in[5];
    const float* bn2_g   = (const float*)d_in[6];
    const float* bn2_b   = (const float*)d_in[7];
    const float* conv3_w = (const float*)d_in[8];
    const float* bn3_g   = (const float*)d_in[9];
    const float* bn3_b   = (const float*)d_in[10];
    const float* conv4_w = (const float*)d_in[11];
    const float* bn4_g   = (const float*)d_in[12];
    const float* bn4_b   = (const float*)d_in[13];
    const float* conv5_w = (const float*)d_in[14];
    const float* lin1_w  = (const float*)d_in[15];
    const float* bn6_g   = (const float*)d_in[16];
    const float* bn6_b   = (const float*)d_in[17];
    const float* lin2_w  = (const float*)d_in[18];
    const float* lin2_b  = (const float*)d_in[19];
    const float* bn7_g   = (const float*)d_in[20];
    const float* bn7_b   = (const float*)d_in[21];
    const float* lin3_w  = (const float*)d_in[22];
    const float* lin3_b  = (const float*)d_in[23];
    float* outp = (float*)d_out;

    // workspace layout (floats): total 10,657,792 f = 42.6 MB
    float* ws   = (float*)d_ws;
    float* xc   = ws;                          // (BN,512)          4,194,304
    int*   idxb = (int*)(ws + 4194304);        // (BN,20)             163,840
    float* nrm  = ws + 4194304 + 163840;       // (BN)                  8,192
    float* ft   = nrm + 8192;                  // (B,<=128,N)       1,048,576
    float* part = ft + 1048576;                // (B,64,1024)         524,288
    float* w5t  = part + 524288;               // (512,1024)          524,288
    float* Ht   = w5t + 524288;                // (BN,<=256)        2,097,152
    float* Ct   = Ht + 2097152;                // (BN,<=256)        2,097,152

    prep_k<<<BN/256, 256, 0, stream>>>(x, ft, nrm);

    // Stage 1: C=3 (coords), O=64, with conv bias
    knn_k<3><<<BN/4, 256, 0, stream>>>(ft, nrm, idxb);
    hc_k<3, 64, true><<<BN/4, 64, 0, stream>>>(x, 3, conv1_w, conv1_b, Ht, Ct);
    gmax_k<64, true><<<BN, 64, 0, stream>>>(Ht, Ct, idxb, bn1_g, bn1_b, xc + 0, ft, nrm);

    // Stage 2: C=64 -> O=64
    knn_k<64><<<BN/4, 256, 0, stream>>>(ft, nrm, idxb);
    hc_k<64, 64, false><<<BN/4, 64, 0, stream>>>(xc + 0, XC_C, conv2_w, nullptr, Ht, Ct);
    gmax_k<64, true><<<BN, 64, 0, stream>>>(Ht, Ct, idxb, bn2_g, bn2_b, xc + 64, ft, nrm);

    // Stage 3: C=64 -> O=128
    knn_k<64><<<BN/4, 256, 0, stream>>>(ft, nrm, idxb);
    hc_k<64, 128, false><<<BN/4, 128, 0, stream>>>(xc + 64, XC_C, conv3_w, nullptr, Ht, Ct);
    gmax_k<128, true><<<BN, 128, 0, stream>>>(Ht, Ct, idxb, bn3_g, bn3_b, xc + 128, ft, nrm);

    // Stage 4: C=128 -> O=256 (no next knn)
    knn_k<128><<<BN/4, 256, 0, stream>>>(ft, nrm, idxb);
    hc_k<128, 256, false><<<BN/4, 256, 0, stream>>>(xc + 128, XC_C, conv4_w, nullptr, Ht, Ct);
    gmax_k<256, false><<<BN, 256, 0, stream>>>(Ht, Ct, idxb, bn4_g, bn4_b, xc + 256, nullptr, nullptr);

    // conv5 + global max pool + head
    w5t_k<<<(512*1024)/256, 256, 0, stream>>>(conv5_w, w5t);
    conv5max_k<<<dim3(64, NB), 256, 0, stream>>>(xc, w5t, part);
    head_k<<<NB, 256, 0, stream>>>(part, lin1_w, bn6_g, bn6_b, lin2_w, lin2_b,
                                   bn7_g, bn7_b, lin3_w, lin3_b, outp);
}

// Round 2
// 808.391 us; speedup vs baseline: 1.0370x; 1.0370x over previous
//
#include <hip/hip_runtime.h>
#include <cmath>
#include <cstdint>
#include <cstddef>

#define NB 8
#define NPTS 1024
#define BN (NB*NPTS)
#define KNN 20
#define XC_C 512
#define BN_SC 0.99999500003749973f  // 1/sqrt(1+1e-5)

static __device__ __forceinline__ float lrelu(float z) { return z >= 0.f ? z : 0.01f * z; }

static __device__ __forceinline__ unsigned long long maxu64(unsigned long long a, unsigned long long b) {
    return a > b ? a : b;
}

// DPP-based max step on a (lo,hi) u64: other = dpp(cur); cur = max(cur, other).
// CTRL: row_ror:1/2/4/8 = 0x121/0x122/0x124/0x128, row_bcast15=0x142, row_bcast31=0x143.
// bound_ctrl=false + old=0 -> lanes with no source contribute 0 (= -inf sentinel).
template<int CTRL>
static __device__ __forceinline__ void dpp_max(unsigned& lo, unsigned& hi) {
    unsigned tlo = (unsigned)__builtin_amdgcn_update_dpp(0, (int)lo, CTRL, 0xF, 0xF, false);
    unsigned thi = (unsigned)__builtin_amdgcn_update_dpp(0, (int)hi, CTRL, 0xF, 0xF, false);
    unsigned long long a = ((unsigned long long)hi << 32) | lo;
    unsigned long long b = ((unsigned long long)thi << 32) | tlo;
    if (b > a) { lo = tlo; hi = thi; }
}

// ---- prep: x (B,N,3) -> ft (B,3,N) + norms ----
__global__ void prep_k(const float* __restrict__ x, float* __restrict__ ft, float* __restrict__ nrm) {
    int i = blockIdx.x * 256 + threadIdx.x;   // b*N+n
    if (i >= BN) return;
    int b = i >> 10, n = i & 1023;
    float a = x[3*i], c = x[3*i+1], d = x[3*i+2];
    float* fb = ft + (size_t)b * 3 * NPTS;
    fb[n] = a; fb[NPTS + n] = c; fb[2*NPTS + n] = d;
    nrm[i] = a*a + c*c + d*d;
}

// ---- fused knn: dist key (2*inner - xx[m]; per-row constant shift preserves jax order+ties)
//      + top-20 via packed-u64 keys and DPP argmax (no DS-pipe shuffles).
// grid BN/4 blocks x 256 threads; one wave per row n.
template<int C>
__global__ __launch_bounds__(256) void knn_k(const float* __restrict__ ft,
                                             const float* __restrict__ frow, int frs,
                                             const float* __restrict__ nrm,
                                             int* __restrict__ idx) {
    int r = blockIdx.x * 4 + (threadIdx.x >> 6);
    int lane = threadIdx.x & 63;
    int b = r >> 10;
    const float* ftb = ft + (size_t)b * C * NPTS;
    float4 acc[4];
#pragma unroll
    for (int j = 0; j < 4; j++) acc[j] = make_float4(0.f, 0.f, 0.f, 0.f);

    if constexpr ((C & 3) == 0) {
        const float4* cr = (const float4*)(frow + (size_t)r * frs);
        for (int c4 = 0; c4 < C/4; c4++) {
            float4 ct4 = cr[c4];
#pragma unroll
            for (int cc = 0; cc < 4; cc++) {
                float ctr = (&ct4.x)[cc];
                const float4* rm = (const float4*)(ftb + (size_t)(4*c4+cc) * NPTS);
#pragma unroll
                for (int j = 0; j < 4; j++) {
                    float4 v = rm[lane + 64*j];
                    acc[j].x = fmaf(ctr, v.x, acc[j].x);
                    acc[j].y = fmaf(ctr, v.y, acc[j].y);
                    acc[j].z = fmaf(ctr, v.z, acc[j].z);
                    acc[j].w = fmaf(ctr, v.w, acc[j].w);
                }
            }
        }
    } else {
        for (int c = 0; c < C; c++) {
            float ctr = frow[(size_t)r * frs + c];
            const float4* rm = (const float4*)(ftb + (size_t)c * NPTS);
#pragma unroll
            for (int j = 0; j < 4; j++) {
                float4 v = rm[lane + 64*j];
                acc[j].x = fmaf(ctr, v.x, acc[j].x);
                acc[j].y = fmaf(ctr, v.y, acc[j].y);
                acc[j].z = fmaf(ctr, v.z, acc[j].z);
                acc[j].w = fmaf(ctr, v.w, acc[j].w);
            }
        }
    }

    // pack keys: hi = order-preserving u32 of (2*inner - xx[m]); lo = 1023-m (lowest-index tiebreak)
    unsigned long long key[16];
    const float4* nm4 = (const float4*)(nrm + b * NPTS);
#pragma unroll
    for (int j = 0; j < 4; j++) {
        float4 nm = nm4[lane + 64*j];
#pragma unroll
        for (int q = 0; q < 4; q++) {
            float f = 2.f * (&acc[j].x)[q] - (&nm.x)[q];
            unsigned u = __float_as_uint(f);
            unsigned s = (unsigned)((int)u >> 31);
            u ^= (s | 0x80000000u);
            int m = 4*(lane + 64*j) + q;
            key[4*j+q] = ((unsigned long long)u << 32) | (unsigned)(1023 - m);
        }
    }

    int mine = 0;
    for (int kk = 0; kk < KNN; kk++) {
        // balanced local max-tree over 16 (chain depth 4)
        unsigned long long b01 = maxu64(key[0], key[1]),  b23 = maxu64(key[2], key[3]);
        unsigned long long b45 = maxu64(key[4], key[5]),  b67 = maxu64(key[6], key[7]);
        unsigned long long b89 = maxu64(key[8], key[9]),  bab = maxu64(key[10], key[11]);
        unsigned long long bcd = maxu64(key[12], key[13]), bef = maxu64(key[14], key[15]);
        unsigned long long q0 = maxu64(b01, b23), q1 = maxu64(b45, b67);
        unsigned long long q2 = maxu64(b89, bab), q3 = maxu64(bcd, bef);
        unsigned long long best = maxu64(maxu64(q0, q1), maxu64(q2, q3));
        unsigned blo = (unsigned)best, bhi = (unsigned)(best >> 32);
        // wave64 max via DPP (VALU pipe, short latency): row reduce then cross-row bcast
        dpp_max<0x121>(blo, bhi);
        dpp_max<0x122>(blo, bhi);
        dpp_max<0x124>(blo, bhi);
        dpp_max<0x128>(blo, bhi);
        dpp_max<0x142>(blo, bhi);   // row_bcast15: row0->1, row1->2, row2->3
        dpp_max<0x143>(blo, bhi);   // row_bcast31: lane31 -> rows 2,3; lane63 = global max
        unsigned wlo = (unsigned)__builtin_amdgcn_readlane((int)blo, 63);
        unsigned whi = (unsigned)__builtin_amdgcn_readlane((int)bhi, 63);
        unsigned long long win = ((unsigned long long)whi << 32) | wlo;
        int m = 1023 - (int)wlo;
        if (lane == kk) mine = m;
        // invalidate winner (u64 keys unique; 0 unreachable => safe sentinel)
#pragma unroll
        for (int t = 0; t < 16; t++) key[t] = (key[t] == win) ? 0ull : key[t];
    }
    if (lane < KNN) idx[r * KNN + lane] = mine;
}

// ---- H/Ct GEMM: Ht[n,o]=F.w1; Ct[n,o]=F.w2 - Ht + bias ----
// grid BN/4, block O; 4 rows per block for w-reuse.
template<int C, int O, bool HASB>
__global__ void hc_k(const float* __restrict__ F, int FS,
                     const float* __restrict__ w, const float* __restrict__ bias,
                     float* __restrict__ Ht, float* __restrict__ Ct) {
    int r0 = blockIdx.x * 4;
    int o = threadIdx.x;
    const float* wr = w + (size_t)o * (2*C);
    float h[4] = {0,0,0,0}, a2[4] = {0,0,0,0};
    if constexpr ((C & 3) == 0) {
        const float4* w1 = (const float4*)wr;
        const float4* w2 = (const float4*)(wr + C);
#pragma unroll 4
        for (int c4 = 0; c4 < C/4; c4++) {
            float4 wa = w1[c4], wb = w2[c4];
#pragma unroll
            for (int nn = 0; nn < 4; nn++) {
                float4 f = *(const float4*)(F + (size_t)(r0+nn)*FS + 4*c4);  // broadcast
                h[nn]  = fmaf(wa.x,f.x, fmaf(wa.y,f.y, fmaf(wa.z,f.z, fmaf(wa.w,f.w, h[nn]))));
                a2[nn] = fmaf(wb.x,f.x, fmaf(wb.y,f.y, fmaf(wb.z,f.z, fmaf(wb.w,f.w, a2[nn]))));
            }
        }
    } else {
        for (int c = 0; c < C; c++) {
            float wa = wr[c], wb = wr[C+c];
#pragma unroll
            for (int nn = 0; nn < 4; nn++) {
                float f = F[(size_t)(r0+nn)*FS + c];
                h[nn]  = fmaf(wa, f, h[nn]);
                a2[nn] = fmaf(wb, f, a2[nn]);
            }
        }
    }
    float bs = 0.f;
    if constexpr (HASB) bs = bias[o];
#pragma unroll
    for (int nn = 0; nn < 4; nn++) {
        size_t ro = (size_t)(r0+nn)*O + o;
        Ht[ro] = h[nn];
        Ct[ro] = a2[nn] - h[nn] + bs;
    }
}

// ---- gather + max_k + bn + lrelu; optional transposed-feature + norms for next knn ----
template<int O, bool WFT>
__global__ void gmax_k(const float* __restrict__ Ht, const float* __restrict__ Ct,
                       const int* __restrict__ idx,
                       const float* __restrict__ g, const float* __restrict__ bb,
                       float* __restrict__ xcs, float* __restrict__ ft, float* __restrict__ nrm) {
    int r = blockIdx.x;
    int b = r >> 10, n = r & 1023;
    int o = threadIdx.x;
    const int* id = idx + r * KNN;
    float vmax = -INFINITY, vmin = INFINITY;
    const float* hb = Ht + (size_t)b * NPTS * O + o;
#pragma unroll 4
    for (int k = 0; k < KNN; k++) {
        int m = id[k];                 // broadcast
        float v = hb[(size_t)m * O];   // coalesced across o
        vmax = fmaxf(vmax, v); vmin = fminf(vmin, v);
    }
    float ct = Ct[(size_t)r * O + o];
    float s = g[o] * BN_SC;
    float pre = (s >= 0.f ? vmax : vmin) + ct;
    float out = lrelu(fmaf(s, pre, bb[o]));
    xcs[(size_t)r * XC_C + o] = out;
    if constexpr (WFT) {
        ft[((size_t)b * O + o) * NPTS + n] = out;
        float sq = out * out;
#pragma unroll
        for (int off = 32; off > 0; off >>= 1) sq += __shfl_xor(sq, off);
        __shared__ float red[O/64 > 0 ? O/64 : 1];
        if ((o & 63) == 0) red[o >> 6] = sq;
        __syncthreads();
        if (o == 0) {
            float t = 0.f;
#pragma unroll
            for (int i = 0; i < O/64; i++) t += red[i];
            nrm[r] = t;
        }
    }
}

// ---- w5 transpose (1024,512) -> (512,1024) for coalesced o-loads ----
__global__ void w5t_k(const float* __restrict__ w5, float* __restrict__ w5t) {
    int i = blockIdx.x * 256 + threadIdx.x;   // c*1024+o
    int c = i >> 10, o = i & 1023;
    w5t[i] = w5[(size_t)o * 512 + c];
}

// ---- conv5 + partial max over n: grid (64 ntiles, B), block 256; thread = 4 o, 16 n ----
__global__ __launch_bounds__(256) void conv5max_k(const float* __restrict__ xc,
                                                  const float* __restrict__ w5t,
                                                  float* __restrict__ part) {
    int b = blockIdx.y, nt = blockIdx.x;
    int o4 = threadIdx.x;
    const float* xb = xc + ((size_t)b * NPTS + nt * 16) * XC_C;
    float4 acc[16];
#pragma unroll
    for (int i = 0; i < 16; i++) acc[i] = make_float4(0.f,0.f,0.f,0.f);
    for (int c = 0; c < 512; c++) {
        float4 w4 = ((const float4*)(w5t + (size_t)c * 1024))[o4];  // coalesced
#pragma unroll
        for (int nn = 0; nn < 16; nn++) {
            float xv = xb[(size_t)nn * XC_C + c];                   // uniform -> scalar path
            acc[nn].x = fmaf(w4.x, xv, acc[nn].x);
            acc[nn].y = fmaf(w4.y, xv, acc[nn].y);
            acc[nn].z = fmaf(w4.z, xv, acc[nn].z);
            acc[nn].w = fmaf(w4.w, xv, acc[nn].w);
        }
    }
    float4 m = acc[0];
#pragma unroll
    for (int nn = 1; nn < 16; nn++) {
        m.x = fmaxf(m.x, acc[nn].x); m.y = fmaxf(m.y, acc[nn].y);
        m.z = fmaxf(m.z, acc[nn].z); m.w = fmaxf(m.w, acc[nn].w);
    }
    ((float4*)(part + ((size_t)b * 64 + nt) * 1024))[o4] = m;
}

// ---- head: reduce partials -> gpool -> lin1/bn6/lrelu -> lin2/bn7/lrelu -> lin3 ----
__global__ __launch_bounds__(256) void head_k(const float* __restrict__ part,
        const float* __restrict__ l1w, const float* __restrict__ g6, const float* __restrict__ b6,
        const float* __restrict__ l2w, const float* __restrict__ l2b,
        const float* __restrict__ g7, const float* __restrict__ b7,
        const float* __restrict__ l3w, const float* __restrict__ l3b,
        float* __restrict__ out) {
    int b = blockIdx.x, t = threadIdx.x;
    __shared__ float gp[1024];
    __shared__ float y1[512];
    __shared__ float y2[256];
    const float* pb = part + (size_t)b * 64 * 1024;
    for (int o = t; o < 1024; o += 256) {
        float m = pb[o];
        for (int j = 1; j < 64; j++) m = fmaxf(m, pb[(size_t)j * 1024 + o]);
        gp[o] = m;
    }
    __syncthreads();
    for (int j = t; j < 512; j += 256) {
        const float4* wr = (const float4*)(l1w + (size_t)j * 1024);
        const float4* g4 = (const float4*)gp;
        float acc = 0.f;
        for (int c = 0; c < 256; c++) {
            float4 w = wr[c], x = g4[c];
            acc = fmaf(w.x,x.x, fmaf(w.y,x.y, fmaf(w.z,x.z, fmaf(w.w,x.w, acc))));
        }
        y1[j] = lrelu(fmaf(acc, g6[j] * BN_SC, b6[j]));
    }
    __syncthreads();
    {
        const float4* wr = (const float4*)(l2w + (size_t)t * 512);
        const float4* y4 = (const float4*)y1;
        float acc = l2b[t];
        for (int c = 0; c < 128; c++) {
            float4 w = wr[c], x = y4[c];
            acc = fmaf(w.x,x.x, fmaf(w.y,x.y, fmaf(w.z,x.z, fmaf(w.w,x.w, acc))));
        }
        y2[t] = lrelu(fmaf(acc, g7[t] * BN_SC, b7[t]));
    }
    __syncthreads();
    if (t < 40) {
        const float4* wr = (const float4*)(l3w + (size_t)t * 256);
        const float4* y4 = (const float4*)y2;
        float acc = l3b[t];
        for (int c = 0; c < 64; c++) {
            float4 w = wr[c], x = y4[c];
            acc = fmaf(w.x,x.x, fmaf(w.y,x.y, fmaf(w.z,x.z, fmaf(w.w,x.w, acc))));
        }
        out[b * 40 + t] = acc;
    }
}

extern "C" void kernel_launch(void* const* d_in, const int* in_sizes, int n_in,
                              void* d_out, int out_size, void* d_ws, size_t ws_size,
                              hipStream_t stream) {
    const float* x       = (const float*)d_in[0];
    const float* conv1_w = (const float*)d_in[1];
    const float* conv1_b = (const float*)d_in[2];
    const float* bn1_g   = (const float*)d_in[3];
    const float* bn1_b   = (const float*)d_in[4];
    const float* conv2_w = (const float*)d_in[5];
    const float* bn2_g   = (const float*)d_in[6];
    const float* bn2_b   = (const float*)d_in[7];
    const float* conv3_w = (const float*)d_in[8];
    const float* bn3_g   = (const float*)d_in[9];
    const float* bn3_b   = (const float*)d_in[10];
    const float* conv4_w = (const float*)d_in[11];
    const float* bn4_g   = (const float*)d_in[12];
    const float* bn4_b   = (const float*)d_in[13];
    const float* conv5_w = (const float*)d_in[14];
    const float* lin1_w  = (const float*)d_in[15];
    const float* bn6_g   = (const float*)d_in[16];
    const float* bn6_b   = (const float*)d_in[17];
    const float* lin2_w  = (const float*)d_in[18];
    const float* lin2_b  = (const float*)d_in[19];
    const float* bn7_g   = (const float*)d_in[20];
    const float* bn7_b   = (const float*)d_in[21];
    const float* lin3_w  = (const float*)d_in[22];
    const float* lin3_b  = (const float*)d_in[23];
    float* outp = (float*)d_out;

    // workspace layout (floats): total 10,657,792 f = 42.6 MB
    float* ws   = (float*)d_ws;
    float* xc   = ws;                          // (BN,512)          4,194,304
    int*   idxb = (int*)(ws + 4194304);        // (BN,20)             163,840
    float* nrm  = ws + 4194304 + 163840;       // (BN)                  8,192
    float* ft   = nrm + 8192;                  // (B,<=128,N)       1,048,576
    float* part = ft + 1048576;                // (B,64,1024)         524,288
    float* w5t  = part + 524288;               // (512,1024)          524,288
    float* Ht   = w5t + 524288;                // (BN,<=256)        2,097,152
    float* Ct   = Ht + 2097152;                // (BN,<=256)        2,097,152

    prep_k<<<BN/256, 256, 0, stream>>>(x, ft, nrm);

    // Stage 1: C=3 (coords), O=64, with conv bias
    knn_k<3><<<BN/4, 256, 0, stream>>>(ft, x, 3, nrm, idxb);
    hc_k<3, 64, true><<<BN/4, 64, 0, stream>>>(x, 3, conv1_w, conv1_b, Ht, Ct);
    gmax_k<64, true><<<BN, 64, 0, stream>>>(Ht, Ct, idxb, bn1_g, bn1_b, xc + 0, ft, nrm);

    // Stage 2: C=64 -> O=64
    knn_k<64><<<BN/4, 256, 0, stream>>>(ft, xc + 0, XC_C, nrm, idxb);
    hc_k<64, 64, false><<<BN/4, 64, 0, stream>>>(xc + 0, XC_C, conv2_w, nullptr, Ht, Ct);
    gmax_k<64, true><<<BN, 64, 0, stream>>>(Ht, Ct, idxb, bn2_g, bn2_b, xc + 64, ft, nrm);

    // Stage 3: C=64 -> O=128
    knn_k<64><<<BN/4, 256, 0, stream>>>(ft, xc + 64, XC_C, nrm, idxb);
    hc_k<64, 128, false><<<BN/4, 128, 0, stream>>>(xc + 64, XC_C, conv3_w, nullptr, Ht, Ct);
    gmax_k<128, true><<<BN, 128, 0, stream>>>(Ht, Ct, idxb, bn3_g, bn3_b, xc + 128, ft, nrm);

    // Stage 4: C=128 -> O=256 (no next knn)
    knn_k<128><<<BN/4, 256, 0, stream>>>(ft, xc + 128, XC_C, nrm, idxb);
    hc_k<128, 256, false><<<BN/4, 256, 0, stream>>>(xc + 128, XC_C, conv4_w, nullptr, Ht, Ct);
    gmax_k<256, false><<<BN, 256, 0, stream>>>(Ht, Ct, idxb, bn4_g, bn4_b, xc + 256, nullptr, nullptr);

    // conv5 + global max pool + head
    w5t_k<<<(512*1024)/256, 256, 0, stream>>>(conv5_w, w5t);
    conv5max_k<<<dim3(64, NB), 256, 0, stream>>>(xc, w5t, part);
    head_k<<<NB, 256, 0, stream>>>(part, lin1_w, bn6_g, bn6_b, lin2_w, lin2_b,
                                   bn7_g, bn7_b, lin3_w, lin3_b, outp);
}